// Round 11
// baseline (240.540 us; speedup 1.0000x reference)
//
#include <hip/hip_runtime.h>
#include <hip/hip_bf16.h>
#include <math.h>

#define B_   4
#define T_   4096
#define DIN_ 1024
#define H_   16
#define D_   64
#define M_   (B_*T_)      // 16384
#define N_   (H_*D_*2)    // 2048
#define K_   DIN_         // 1024
#define C_   64           // scan chunks per (b,h) chain
#define CL_  (T_/C_)      // 64 steps per chunk

typedef unsigned short u16;
typedef __attribute__((ext_vector_type(8))) short short8_t;
typedef __attribute__((ext_vector_type(16))) float f32x16;

__device__ __forceinline__ u16 f2bf(float f) {
  unsigned int x = __float_as_uint(f);
  x += 0x7fffu + ((x >> 16) & 1u);   // round-to-nearest-even (finite inputs)
  return (u16)(x >> 16);
}
__device__ __forceinline__ float bf2f(unsigned int u) {
  return __uint_as_float((u & 0xffffu) << 16);
}
__device__ __forceinline__ unsigned pk_bf16(float x, float y) {
  float2 f; f.x = x; f.y = y;
  union { __hip_bfloat162 h2; unsigned u; } c;
  c.h2 = __float22bfloat162_rn(f);
  return c.u;
}

// async global->LDS, 16 B per lane. LDS dest = wave-uniform base + lane*16.
__device__ __forceinline__ void g2l16(const u16* g, u16* l) {
  __builtin_amdgcn_global_load_lds(
      (const __attribute__((address_space(1))) void*)g,
      (__attribute__((address_space(3))) void*)l, 16, 0, 0);
}

// ---------------- prep: cast inputs (dense loads) + cast-transpose weights -------------
__global__ __launch_bounds__(256)
void prep(const float* __restrict__ inputs, const float* __restrict__ kvk,
          u16* __restrict__ aB, u16* __restrict__ wBt) {
  __shared__ float tile[32][33];
  int bid = blockIdx.x;
  int tid = threadIdx.x;
  if (bid < 8192) {
    // two fully-dense passes over M*K/4 float4s
    int j = bid * 256 + tid;            // 0..2097151
    const float4* s4 = (const float4*)inputs;
    float4 a = s4[j];
    float4 b = s4[j + 2097152];
    uint2 oa; oa.x = pk_bf16(a.x, a.y); oa.y = pk_bf16(a.z, a.w);
    uint2 ob; ob.x = pk_bf16(b.x, b.y); ob.y = pk_bf16(b.z, b.w);
    ((uint2*)aB)[j]           = oa;
    ((uint2*)aB)[j + 2097152] = ob;
  } else {
    int b2 = bid - 8192;              // 2048 blocks
    int kb = (b2 & 31) * 32;          // K/32 = 32
    int nb = (b2 >> 5) * 32;          // N/32 = 64
    int r  = tid >> 3;                // 0..31
    int c4 = (tid & 7) * 4;           // 0..28
    float4 v = *(const float4*)&kvk[(size_t)(kb + r) * N_ + nb + c4];
    tile[r][c4+0] = v.x; tile[r][c4+1] = v.y; tile[r][c4+2] = v.z; tile[r][c4+3] = v.w;
    __syncthreads();
    uint2 o;
    o.x = pk_bf16(tile[c4+0][r], tile[c4+1][r]);
    o.y = pk_bf16(tile[c4+2][r], tile[c4+3][r]);
    *(uint2*)&wBt[(size_t)(nb + r) * K_ + kb + c4] = o;
  }
}

// ---------------- gemm_kv R11: R7 shell (HW-proven) + sched_barrier region pinning ------
// 1024 thr = 16 waves (4x4 of 64x64 tiles, 2x2 frags of 32x32). K-step = 16.
// LDS 4 parities x (A 8KB + B 8KB) = 64 KB, fragment-major (conflict-free):
//   subtile (32 rows x k16 = 1 KB): granule g = (row = g&31, khalf = g>>5);
//   staging source permuted to match; g2l16 dest linear.
// Phase kt: { 4 ds_read(kt+1 -> other reg set) | 1 g2l16 stage(kt+3) }
//           SCHED_BARRIER(0)              <- R11: pin mem-block BEFORE MFMAs
//           { 4 MFMA(kt) on regs loaded last phase }
//           SCHED_BARRIER(0)              <- R11: pin MFMAs BEFORE vmcnt/barrier
//           vmcnt(1); barrier.
// Rationale (guide rule #18 / m201 template): MFMAs are register-only, so
// asm-"memory" fences do NOT order them; without sched_barrier the compiler
// can sink this phase's ds_reads below the MFMA cluster, re-creating the
// load->compute convoy (R7 measured 2006 cyc/phase vs ~800 floor).
// RAW: vmcnt(1) at end of phase kt leaves only stage(kt+3) outstanding =>
//   stage(kt+2) landed => phase kt+1 may ds_read par (kt+2)&3. ✓
// WAR: stage(kt+3) overwrites par (kt-1)&3 whose reads were register-consumed
//   by MFMA(kt-1) before the previous barrier. ✓

#define FENCE asm volatile("" ::: "memory")
#define KBAR do { FENCE; __builtin_amdgcn_s_barrier(); FENCE; } while (0)
#define SCB0 __builtin_amdgcn_sched_barrier(0)

#define MFMA32(a,b,c) __builtin_amdgcn_mfma_f32_32x32x16_bf16(a,b,c,0,0,0)

#define LOADS(PN, AF, BF) do { \
  AF[0] = *(const short8_t*)&lds[(PN)*4096 + aOff      ]; \
  AF[1] = *(const short8_t*)&lds[(PN)*4096 + aOff + 512]; \
  BF[0] = *(const short8_t*)&lds[16384 + (PN)*4096 + bOff      ]; \
  BF[1] = *(const short8_t*)&lds[16384 + (PN)*4096 + bOff + 512]; \
} while (0)

#define MMAS(AF, BF) do { \
  __builtin_amdgcn_s_setprio(1); \
  acc[0][0] = MFMA32(AF[0], BF[0], acc[0][0]); \
  acc[0][1] = MFMA32(AF[0], BF[1], acc[0][1]); \
  acc[1][0] = MFMA32(AF[1], BF[0], acc[1][0]); \
  acc[1][1] = MFMA32(AF[1], BF[1], acc[1][1]); \
  __builtin_amdgcn_s_setprio(0); \
} while (0)

#define PHASE(KT, PN, PS, AFm, BFm, AFl, BFl) do { \
  LOADS(PN, AFl, BFl); \
  g2l16(gS + (size_t)((KT)+3)*16, lds + stBase + (PS)*4096); \
  SCB0; \
  MMAS(AFm, BFm); \
  SCB0; \
  asm volatile("s_waitcnt vmcnt(1)" ::: "memory"); \
  KBAR; \
} while (0)

__global__ __launch_bounds__(1024)
void gemm_kv(const u16* __restrict__ A, const u16* __restrict__ Bt,
             const float* __restrict__ q,
             float* __restrict__ pbuf, u16* __restrict__ vbuf,
             float* __restrict__ aggU, float* __restrict__ aggW) {
  extern __shared__ __align__(16) char smem[];
  u16* lds = (u16*)smem;

  const int tid  = threadIdx.x;
  const int wv   = tid >> 6;          // 0..15
  const int lane = tid & 63;
  const int l31  = lane & 31;
  const int hi   = lane >> 5;
  const int wr2  = wv >> 2;           // 0..3  (m: 64-row group)
  const int wc2  = wv & 3;            // 0..3  (n: 64-col group)

  // XCD-aware bijective swizzle (512 % 8 == 0)
  const int g  = blockIdx.x;
  const int wg = (g & 7) * 64 + (g >> 3);
  const int nt = wg & 7;              // heads {2nt, 2nt+1}
  const int mt = wg >> 3;             // rows [mt*256, +256)
  const int bm = mt * 256;
  const int bn = nt * 256;

  // staging: waves 0-7 stage A rows [wv*32,+32), waves 8-15 stage B likewise.
  // fragment-major source permutation: lane l loads row l&31, khalf l>>5.
  const int stBase = (wv < 8) ? wv * 512 : 16384 + (wv - 8) * 512;
  const u16* gS = (wv < 8)
    ? A  + (size_t)(bm + wv*32     + l31) * K_ + hi * 8
    : Bt + (size_t)(bn + (wv-8)*32 + l31) * K_ + hi * 8;

  // fragment ds_read bases (u16): subtile (wr2*2+i) at (wr2*2+i)*512, +lane*8
  const int aOff = wr2 * 1024 + lane * 8;            // + par*4096 + i*512
  const int bOff = wc2 * 1024 + lane * 8;            // + 16384 + par*4096 + j*512

  f32x16 acc[2][2] = {};
  short8_t af0[2], bf0[2], af1[2], bf1[2];

  // prologue: stage kt0,kt1,kt2; wait kt0+kt1; barrier; preload kt0 frags -> set0
  g2l16(gS,      lds + stBase + 0*4096);
  g2l16(gS + 16, lds + stBase + 1*4096);
  g2l16(gS + 32, lds + stBase + 2*4096);
  asm volatile("s_waitcnt vmcnt(1)" ::: "memory");
  KBAR;
  LOADS(0, af0, bf0);

  // main: kt = 0..55 (7 x 8 phases); every phase stages kt+3 (<= 58)
#pragma unroll 1
  for (int kq = 0; kq < 7; ++kq) {
    const int kt = kq * 8;
    PHASE(kt+0, 1, 3, af0, bf0, af1, bf1);
    PHASE(kt+1, 2, 0, af1, bf1, af0, bf0);
    PHASE(kt+2, 3, 1, af0, bf0, af1, bf1);
    PHASE(kt+3, 0, 2, af1, bf1, af0, bf0);
    PHASE(kt+4, 1, 3, af0, bf0, af1, bf1);
    PHASE(kt+5, 2, 0, af1, bf1, af0, bf0);
    PHASE(kt+6, 3, 1, af0, bf0, af1, bf1);
    PHASE(kt+7, 0, 2, af1, bf1, af0, bf0);
  }
  // tail kt = 56..63
  PHASE(56, 1, 3, af0, bf0, af1, bf1);   // stage 59
  PHASE(57, 2, 0, af1, bf1, af0, bf0);   // stage 60
  PHASE(58, 3, 1, af0, bf0, af1, bf1);   // stage 61
  PHASE(59, 0, 2, af1, bf1, af0, bf0);   // stage 62
  PHASE(60, 1, 3, af0, bf0, af1, bf1);   // stage 63
  {  // kt=61: read kt62 (par 2), no stage, drain
    LOADS(2, af0, bf0);
    SCB0;
    MMAS(af1, bf1);
    SCB0;
    asm volatile("s_waitcnt vmcnt(0)" ::: "memory");
    KBAR;
  }
  {  // kt=62: read kt63 (par 3)
    LOADS(3, af1, bf1);
    SCB0;
    MMAS(af0, bf0);
    KBAR;
  }
  MMAS(af1, bf1);                        // kt=63

  // ---------------- fused epilogue (32x32 C/D layout) — R7-verbatim ----------------
  // C/D: col(n) = l31, row = (reg&3) + 8*(reg>>2) + 4*hi.
  // t = wr2*64 + i*32 + row;  n' = wc2*64 + j*32 + l31; head nh = wc2>>1,
  // col-half wc2p = wc2&1. parity(n') = parity(l31):
  //   odd l31 -> v column d = wc2p*32 + j*16 + (l31>>1)
  //   even l31 -> k column (dot with q, reduce over 16 even lanes per hi-half)
  u16*   vtile = (u16*)smem;                  // [2][256][72] u16 = 73728 B
  float* sred  = (float*)(smem + 73728);      // [2][256][5]  f32 = 10240 B
  float* pS    = (float*)(smem + 83968);      // [2][256]     f32 =  2048 B (end 86016)

  __syncthreads();   // all K-loop LDS reads complete before overlay writes

  const int nh   = wc2 >> 1;
  const int wc2p = wc2 & 1;

  float qv[2];
  qv[0] = q[(nt*2 + nh)*64 + wc2p*32 +  0 + (l31 >> 1)];
  qv[1] = q[(nt*2 + nh)*64 + wc2p*32 + 16 + (l31 >> 1)];

#pragma unroll
  for (int i = 0; i < 2; ++i) {
#pragma unroll
    for (int reg = 0; reg < 16; ++reg) {
      const int t = wr2*64 + i*32 + (reg & 3) + 8*(reg >> 2) + 4*hi;
      const float x0 = fmaxf(acc[i][0][reg], 0.f);
      const float x1 = fmaxf(acc[i][1][reg], 0.f);
      if (l31 & 1) {
        const int d0 = wc2p*32 + (l31 >> 1);
        vtile[(nh*256 + t)*72 + d0     ] = f2bf(x0);
        vtile[(nh*256 + t)*72 + d0 + 16] = f2bf(x1);
      } else {
        float ps = qv[0]*x0 + qv[1]*x1;
        ps += __shfl_xor(ps, 2);
        ps += __shfl_xor(ps, 4);
        ps += __shfl_xor(ps, 8);
        ps += __shfl_xor(ps, 16);
        if (l31 == 0)
          sred[(nh*256 + t)*5 + wc2p] = ps;
      }
    }
  }
  __syncthreads();

  const int b  = mt >> 4;             // 16 m-tiles per batch
  const int t0 = (mt & 15) * 256;
  if (tid < 512) {
    // p-phase: wave = one (hh, 64-t chunk); U via shuffle reduce
    const int hh = tid >> 8;
    const int t  = tid & 255;
    const float* sr = &sred[(hh*256 + t)*5];
    float s = sr[0] + sr[1];
    float p = __expf(fminf(fmaxf(s, -60.f), 60.f));
    pS[hh*256 + t] = p;
    pbuf[(size_t)(b*H_ + nt*2 + hh) * T_ + t0 + t] = p;
    float u = p;
#pragma unroll
    for (int off = 32; off; off >>= 1) u += __shfl_down(u, off);
    if (lane == 0)
      aggU[(b*H_ + nt*2 + hh)*C_ + (mt & 15)*4 + ((tid >> 6) & 3)] = u;
  }
  __syncthreads();

  if (l31 & 1) {
    // W straight from acc (odd lanes hold v columns). Wave's t-range is one
    // 64-t chunk (wr2); hi halves combined via xor-32 shuffle.
    float Wv0 = 0.f, Wv1 = 0.f;
#pragma unroll
    for (int i = 0; i < 2; ++i)
#pragma unroll
      for (int reg = 0; reg < 16; ++reg) {
        const int t = wr2*64 + i*32 + (reg & 3) + 8*(reg >> 2) + 4*hi;
        const float p = pS[nh*256 + t];
        Wv0 += p * fmaxf(acc[i][0][reg], 0.f);
        Wv1 += p * fmaxf(acc[i][1][reg], 0.f);
      }
    Wv0 += __shfl_xor(Wv0, 32);
    Wv1 += __shfl_xor(Wv1, 32);
    if (hi == 0) {
      const int blk = (b*H_ + nt*2 + nh)*C_ + (mt & 15)*4 + wr2;
      aggW[(size_t)blk * D_ + wc2p*32 +  0 + (l31 >> 1)] = Wv0;
      aggW[(size_t)blk * D_ + wc2p*32 + 16 + (l31 >> 1)] = Wv1;
    }
  }
  {
    // coalesced v store: 512 rows x 128 B (vbuf flat [bh][t][d])
    const int d0 = (tid & 7) * 8;
#pragma unroll
    for (int k2 = 0; k2 < 4; ++k2) {
      const int row = (tid >> 3) + 128*k2;   // 0..511
      const int hh  = row >> 8;
      const int t   = row & 255;
      uint4 val = *(const uint4*)&vtile[(hh*256 + t)*72 + d0];
      *(uint4*)&vbuf[((size_t)(b*H_ + nt*2 + hh) * T_ + t0 + t) * D_ + d0] = val;
    }
  }
}

// ---------------- pass 3: additive prefix + seeded scan + h-reduction (unchanged) ------
__global__ __launch_bounds__(1024)
void scan_pass3(const u16* __restrict__ vbuf, const float* __restrict__ pbuf,
                const float* __restrict__ aggU, const float* __restrict__ aggW,
                float* __restrict__ out) {
  __shared__ float pS[H_][CL_];         // 4 KB
  __shared__ float wbuf[H_][8][D_ + 1]; // 33.3 KB
  int bc = blockIdx.x;
  int b  = bc >> 6;
  int c  = bc & (C_ - 1);
  int tid  = threadIdx.x;
  int h    = tid >> 6;
  int lane = tid & 63;
  int bh   = b * H_ + h;
  int t0   = c * CL_;

  pS[h][lane] = pbuf[(size_t)bh * T_ + t0 + lane];

  // additive exclusive prefix over chunks [0,c): independent loads, pipelines freely
  float U = 0.f, W = 0.f;
  for (int j = 0; j < c; ++j) {
    int idx = bh * C_ + j;
    U += aggU[idx];
    W += aggW[(size_t)idx * D_ + lane];
  }
  __syncthreads();

  const u16* vp = vbuf + ((size_t)bh * T_ + t0) * D_ + lane;
  for (int gg = 0; gg < 8; ++gg) {
#pragma unroll
    for (int ii = 0; ii < 8; ++ii) {
      int i = gg * 8 + ii;
      float p = pS[h][i];
      float v = bf2f(vp[i * D_]);
      U += p;
      W += p * v;
      wbuf[h][ii][lane] = __fdividef(W, U);
    }
    __syncthreads();
    if (tid < 512) {
      int ii = tid >> 6, dd = tid & 63;
      float acc = 0.f;
#pragma unroll
      for (int hh = 0; hh < H_; ++hh) acc += wbuf[hh][ii][dd];
      out[((size_t)b * T_ + t0 + gg*8 + ii) * D_ + dd] = acc;
    }
    __syncthreads();
  }
}

extern "C" void kernel_launch(void* const* d_in, const int* in_sizes, int n_in,
                              void* d_out, int out_size, void* d_ws, size_t ws_size,
                              hipStream_t stream) {
  const float* inputs = (const float*)d_in[0];   // (B,T,DIN)
  const float* kvk    = (const float*)d_in[1];   // (DIN,H,D,2)
  const float* qk     = (const float*)d_in[2];   // (H,D)
  float* out = (float*)d_out;
  char* ws = (char*)d_ws;

  u16*   aB   = (u16*)ws;                       // 33,554,432 B  inputs bf16 [M][K]
  u16*   wBt  = (u16*)(ws + 33554432);          //  4,194,304 B  weights bf16 [N][K]
  u16*   vb   = (u16*)(ws + 37748736);          // 33,554,432 B  v bf16 [b,h,t,d]
  float* pb   = (float*)(ws + 71303168);        //  1,048,576 B  p=exp(s) [b,h,t]
  float* aggU = (float*)(ws + 72351744);        //     16,384 B
  float* aggW = (float*)(ws + 72368128);        //  1,048,576 B  (ends ~73.4 MB)

  prep<<<10240, 256, 0, stream>>>(inputs, kvk, aB, wBt);
  gemm_kv<<<512, 1024, 86016, stream>>>(aB, wBt, qk, pb, vb, aggU, aggW);
  scan_pass3<<<B_*C_, 1024, 0, stream>>>(vb, pb, aggU, aggW, out);
}

// Round 12
// 201.051 us; speedup vs baseline: 1.1964x; 1.1964x over previous
//
#include <hip/hip_runtime.h>
#include <hip/hip_bf16.h>
#include <math.h>

#define B_   4
#define T_   4096
#define DIN_ 1024
#define H_   16
#define D_   64
#define M_   (B_*T_)      // 16384
#define N_   (H_*D_*2)    // 2048
#define K_   DIN_         // 1024
#define C_   64           // scan chunks per (b,h) chain
#define CL_  (T_/C_)      // 64 steps per chunk

typedef unsigned short u16;
typedef __attribute__((ext_vector_type(8))) short short8_t;
typedef __attribute__((ext_vector_type(4))) float float4_t;

__device__ __forceinline__ u16 f2bf(float f) {
  unsigned int x = __float_as_uint(f);
  x += 0x7fffu + ((x >> 16) & 1u);   // round-to-nearest-even (finite inputs)
  return (u16)(x >> 16);
}
__device__ __forceinline__ float bf2f(unsigned int u) {
  return __uint_as_float((u & 0xffffu) << 16);
}
__device__ __forceinline__ unsigned pk_bf16(float x, float y) {
  float2 f; f.x = x; f.y = y;
  union { __hip_bfloat162 h2; unsigned u; } c;
  c.h2 = __float22bfloat162_rn(f);
  return c.u;
}

// async global->LDS, 16 B per lane. LDS dest = wave-uniform base + lane*16.
__device__ __forceinline__ void g2l16(const u16* g, u16* l) {
  __builtin_amdgcn_global_load_lds(
      (const __attribute__((address_space(1))) void*)g,
      (__attribute__((address_space(3))) void*)l, 16, 0, 0);
}

// ---------------- prep: cast inputs + cast-transpose weights (R5-exact) ----------------
__global__ __launch_bounds__(256)
void prep(const float* __restrict__ inputs, const float* __restrict__ kvk,
          u16* __restrict__ aB, u16* __restrict__ wBt) {
  __shared__ float tile[32][33];
  int bid = blockIdx.x;
  int tid = threadIdx.x;
  if (bid < 8192) {
    int i = bid * 256 + tid;          // over M*K/8
    const float4* src = (const float4*)inputs;
    float4 a = src[2*i], b = src[2*i+1];
    uint4 o;
    o.x = pk_bf16(a.x, a.y);
    o.y = pk_bf16(a.z, a.w);
    o.z = pk_bf16(b.x, b.y);
    o.w = pk_bf16(b.z, b.w);
    ((uint4*)aB)[i] = o;
  } else {
    int b2 = bid - 8192;              // 2048 blocks
    int kb = (b2 & 31) * 32;          // K/32 = 32
    int nb = (b2 >> 5) * 32;          // N/32 = 64
    int r  = tid >> 3;                // 0..31
    int c4 = (tid & 7) * 4;           // 0..28
    float4 v = *(const float4*)&kvk[(size_t)(kb + r) * N_ + nb + c4];
    tile[r][c4+0] = v.x; tile[r][c4+1] = v.y; tile[r][c4+2] = v.z; tile[r][c4+3] = v.w;
    __syncthreads();
    uint2 o;
    o.x = pk_bf16(tile[c4+0][r], tile[c4+1][r]);
    o.y = pk_bf16(tile[c4+2][r], tile[c4+3][r]);
    *(uint2*)&wBt[(size_t)(nb + r) * K_ + kb + c4] = o;
  }
}

// ---------------- gemm_kv R5 (session-best shell): 256x256, 16 waves, BK=32, 3-buf -----
// 1024 thr = 16 waves (4x4), wave tile 64x64. LDS 96 KB:
//   A[par 3][256 rows][32 u16]  @ par*8192 u16   (16 KB per parity)
//   B[par 3][256 rows][32 u16]  @ 24576 + par*8192 u16
// Row = 32 u16 (64 B), granule = 8 u16 (16 B); swizzle g' = g ^ ((row>>1)&3)
// (max 2-way bank aliasing = free), pre-XOR'd on the global source.
// Phase (= one K-tile, BK=32), ALL phases identical:
//   8 ds_read_b128 (4 A-frags + 4 B-frags, par kt%3)
//   2 g2l16        (stage K-tile kt+2 into par (kt+2)%3  -- never the read par!)
//   barrier; 16 MFMA (setprio); s_waitcnt vmcnt(2); barrier
// vmcnt(2) leaves this phase's own 2 stage-loads in flight and guarantees
// kt+1's stages (issued last phase) landed. Counted wait every phase, no
// drain-0 until the 2-phase tail. 32 phases, 64 barriers/block.

#define FENCE asm volatile("" ::: "memory")
#define KBAR do { FENCE; __builtin_amdgcn_s_barrier(); FENCE; } while (0)

#define READS(PAR) do { _Pragma("unroll") \
  for (int i_ = 0; i_ < 4; ++i_) \
    af[i_] = *(const short8_t*)&lds[(PAR)*8192 + aBase + i_*512]; \
  _Pragma("unroll") \
  for (int j_ = 0; j_ < 4; ++j_) \
    bfq[j_] = *(const short8_t*)&lds[(PAR)*8192 + bBase + j_*512]; \
} while (0)

#define MFMAS do { \
  __builtin_amdgcn_s_setprio(1); \
  _Pragma("unroll") for (int i_ = 0; i_ < 4; ++i_) \
  _Pragma("unroll") for (int j_ = 0; j_ < 4; ++j_) \
    acc[i_][j_] = __builtin_amdgcn_mfma_f32_16x16x32_bf16( \
        af[i_], bfq[j_], acc[i_][j_], 0, 0, 0); \
  __builtin_amdgcn_s_setprio(0); \
} while (0)

#define PHASE(PAR, PAR2, KT) do { \
  short8_t af[4], bfq[4]; \
  READS(PAR); \
  g2l16(gA + ((KT)+2)*32, lds +         (PAR2)*8192 + wv*512); \
  g2l16(gB + ((KT)+2)*32, lds + 24576 + (PAR2)*8192 + wv*512); \
  KBAR; \
  MFMAS; \
  asm volatile("s_waitcnt vmcnt(2)" ::: "memory"); \
  KBAR; \
} while (0)

__global__ __launch_bounds__(1024)
void gemm_kv(const u16* __restrict__ A, const u16* __restrict__ Bt,
             const float* __restrict__ q,
             float* __restrict__ pbuf, u16* __restrict__ vbuf,
             float* __restrict__ aggU, float* __restrict__ aggW) {
  extern __shared__ __align__(16) char smem[];
  u16* lds = (u16*)smem;

  const int tid  = threadIdx.x;
  const int wv   = tid >> 6;          // 0..15
  const int lane = tid & 63;
  const int quad = lane >> 4;
  const int l16  = lane & 15;
  const int wr2  = wv >> 2;           // 0..3  (m: 64-row group)
  const int wc2  = wv & 3;            // 0..3  (n: 64-col group)

  // XCD-aware bijective swizzle (512 % 8 == 0)
  const int g  = blockIdx.x;
  const int wg = (g & 7) * 64 + (g >> 3);
  const int nt = wg & 7;              // heads {2nt, 2nt+1}
  const int mt = wg >> 3;             // rows [mt*256, +256)
  const int bm = mt * 256;
  const int bn = nt * 256;

  // staging: thread -> (row = tid>>2, granule = tid&3), global src pre-XOR'd
  const u16* gA = A  + (size_t)(bm + (tid >> 2)) * K_ + (((tid & 3) ^ ((tid >> 3) & 3)) * 8);
  const u16* gB = Bt + (size_t)(bn + (tid >> 2)) * K_ + (((tid & 3) ^ ((tid >> 3) & 3)) * 8);

  // fragment ds_read bases (u16): row = {wr2|wc2}*64 + frag*16 + l16, stride 32
  const int sg    = (quad ^ ((l16 >> 1) & 3)) * 8;   // swizzled granule
  const int aBase = wr2 * 2048 + l16 * 32 + sg;            // + par*8192 + i*512
  const int bBase = 24576 + wc2 * 2048 + l16 * 32 + sg;    // + par*8192 + j*512

  float4_t acc[4][4] = {};

  // prologue: stage kt0, kt1; verify kt0; barrier
  g2l16(gA,      lds +                 wv*512);
  g2l16(gB,      lds + 24576 +         wv*512);
  g2l16(gA + 32, lds +          8192 + wv*512);
  g2l16(gB + 32, lds + 24576 +  8192 + wv*512);
  asm volatile("s_waitcnt vmcnt(2)" ::: "memory");
  KBAR;

  // main loop: kt = 0..29 (kt+2 <= 31 always stages)
#pragma unroll 1
  for (int kq = 0; kq < 10; ++kq) {
    const int kt = kq * 3;
    PHASE(0, 2, kt + 0);
    PHASE(1, 0, kt + 1);
    PHASE(2, 1, kt + 2);
  }
  // tail kt=30 (par 0): no stage; drain
  {
    short8_t af[4], bfq[4];
    READS(0);
    KBAR;
    MFMAS;
    asm volatile("s_waitcnt vmcnt(0)" ::: "memory");
    KBAR;
  }
  // tail kt=31 (par 1): everything resident
  {
    short8_t af[4], bfq[4];
    READS(1);
    KBAR;
    MFMAS;
    KBAR;
  }

  // ---------------- fused epilogue (R5, 16-wave mapping) ----------------
  // C/D frag: col(n) = l16, row(m) = quad*4 + reg.
  // t = wr2*64 + i*16 + quad*4 + r;  n' = wc2*64 + j*16 + l16.
  // head-local nh = wc2>>1; col-half wc2p = wc2&1. parity(n') = parity(l16):
  // odd -> v column d = wc2p*32 + j*8 + (l16>>1); even -> k column (dot with q).
  u16*   vtile = (u16*)smem;                  // [2][256][72] u16 = 73728 B
  float* sred  = (float*)(smem + 73728);      // [2][256][5]  f32 = 10240 B
  float* pS    = (float*)(smem + 83968);      // [2][256]     f32 =  2048 B (end 86016)

  const int nh   = wc2 >> 1;
  const int wc2p = wc2 & 1;
  const int hd   = l16 >> 1;

  float qv[4];
#pragma unroll
  for (int j = 0; j < 4; ++j)
    qv[j] = q[(nt*2 + nh)*64 + wc2p*32 + j*8 + hd];

#pragma unroll
  for (int i = 0; i < 4; ++i) {
#pragma unroll
    for (int r = 0; r < 4; ++r) {
      const int t = wr2*64 + i*16 + quad*4 + r;
      float x0 = fmaxf(acc[i][0][r], 0.f);
      float x1 = fmaxf(acc[i][1][r], 0.f);
      float x2 = fmaxf(acc[i][2][r], 0.f);
      float x3 = fmaxf(acc[i][3][r], 0.f);
      if (l16 & 1) {               // v columns -> staged transpose
        vtile[(nh*256 + t)*72 + wc2p*32 +  0 + hd] = f2bf(x0);
        vtile[(nh*256 + t)*72 + wc2p*32 +  8 + hd] = f2bf(x1);
        vtile[(nh*256 + t)*72 + wc2p*32 + 16 + hd] = f2bf(x2);
        vtile[(nh*256 + t)*72 + wc2p*32 + 24 + hd] = f2bf(x3);
      } else {                     // k columns: q-dot partials
        float ps = qv[0]*x0 + qv[1]*x1 + qv[2]*x2 + qv[3]*x3;
        ps += __shfl_xor(ps, 2);
        ps += __shfl_xor(ps, 4);
        if ((l16 & 7) == 0)
          sred[(nh*256 + t)*5 + wc2p*2 + (l16 >> 3)] = ps;
      }
    }
  }
  __syncthreads();

  const int b  = mt >> 4;             // 16 m-tiles per batch
  const int t0 = (mt & 15) * 256;
  if (tid < 512) {
    // p-phase: wave = one (hh, 64-t chunk); U via shuffle reduce
    const int hh = tid >> 8;
    const int t  = tid & 255;
    const float* sr = &sred[(hh*256 + t)*5];
    float s = sr[0] + sr[1] + sr[2] + sr[3];
    float p = __expf(fminf(fmaxf(s, -60.f), 60.f));
    pS[hh*256 + t] = p;
    pbuf[(size_t)(b*H_ + nt*2 + hh) * T_ + t0 + t] = p;
    float u = p;
#pragma unroll
    for (int off = 32; off; off >>= 1) u += __shfl_down(u, off);
    if (lane == 0)
      aggU[(b*H_ + nt*2 + hh)*C_ + (mt & 15)*4 + ((tid >> 6) & 3)] = u;
  }
  __syncthreads();

  if (l16 & 1) {
    // W aggregates straight from acc (odd lanes hold v columns); wave's t-range
    // is exactly one 64-t chunk (wr2), one head (nh), one col-half (wc2p).
    float Wv[4] = {};
#pragma unroll
    for (int i = 0; i < 4; ++i)
#pragma unroll
      for (int r = 0; r < 4; ++r) {
        const int t = wr2*64 + i*16 + quad*4 + r;
        const float p = pS[nh*256 + t];
        Wv[0] += p * fmaxf(acc[i][0][r], 0.f);
        Wv[1] += p * fmaxf(acc[i][1][r], 0.f);
        Wv[2] += p * fmaxf(acc[i][2][r], 0.f);
        Wv[3] += p * fmaxf(acc[i][3][r], 0.f);
      }
#pragma unroll
    for (int j = 0; j < 4; ++j) {
      float w = Wv[j];
      w += __shfl_xor(w, 16);       // reduce across quads (t within chunk)
      w += __shfl_xor(w, 32);
      if (quad == 0) {
        const int blk = (b*H_ + nt*2 + nh)*C_ + (mt & 15)*4 + wr2;
        aggW[(size_t)blk * D_ + wc2p*32 + j*8 + hd] = w;
      }
    }
  }
  {
    // coalesced v store: 512 rows x 128 B (vbuf flat [bh][t][d])
    const int d0 = (tid & 7) * 8;
#pragma unroll
    for (int k2 = 0; k2 < 4; ++k2) {
      const int row = (tid >> 3) + 128*k2;   // 0..511
      const int hh  = row >> 8;
      const int t   = row & 255;
      uint4 val = *(const uint4*)&vtile[(hh*256 + t)*72 + d0];
      *(uint4*)&vbuf[((size_t)(b*H_ + nt*2 + hh) * T_ + t0 + t) * D_ + d0] = val;
    }
  }
}

// ---------------- pass 3: additive prefix + seeded scan + h-reduction (R5-exact) -------
__global__ __launch_bounds__(1024)
void scan_pass3(const u16* __restrict__ vbuf, const float* __restrict__ pbuf,
                const float* __restrict__ aggU, const float* __restrict__ aggW,
                float* __restrict__ out) {
  __shared__ float pS[H_][CL_];         // 4 KB
  __shared__ float wbuf[H_][8][D_ + 1]; // 33.3 KB
  int bc = blockIdx.x;
  int b  = bc >> 6;
  int c  = bc & (C_ - 1);
  int tid  = threadIdx.x;
  int h    = tid >> 6;
  int lane = tid & 63;
  int bh   = b * H_ + h;
  int t0   = c * CL_;

  pS[h][lane] = pbuf[(size_t)bh * T_ + t0 + lane];

  // additive exclusive prefix over chunks [0,c): independent loads, pipelines freely
  float U = 0.f, W = 0.f;
  for (int j = 0; j < c; ++j) {
    int idx = bh * C_ + j;
    U += aggU[idx];
    W += aggW[(size_t)idx * D_ + lane];
  }
  __syncthreads();

  const u16* vp = vbuf + ((size_t)bh * T_ + t0) * D_ + lane;
  for (int gg = 0; gg < 8; ++gg) {
#pragma unroll
    for (int ii = 0; ii < 8; ++ii) {
      int i = gg * 8 + ii;
      float p = pS[h][i];
      float v = bf2f(vp[i * D_]);
      U += p;
      W += p * v;
      wbuf[h][ii][lane] = __fdividef(W, U);
    }
    __syncthreads();
    if (tid < 512) {
      int ii = tid >> 6, dd = tid & 63;
      float acc = 0.f;
#pragma unroll
      for (int hh = 0; hh < H_; ++hh) acc += wbuf[hh][ii][dd];
      out[((size_t)b * T_ + t0 + gg*8 + ii) * D_ + dd] = acc;
    }
    __syncthreads();
  }
}

extern "C" void kernel_launch(void* const* d_in, const int* in_sizes, int n_in,
                              void* d_out, int out_size, void* d_ws, size_t ws_size,
                              hipStream_t stream) {
  const float* inputs = (const float*)d_in[0];   // (B,T,DIN)
  const float* kvk    = (const float*)d_in[1];   // (DIN,H,D,2)
  const float* qk     = (const float*)d_in[2];   // (H,D)
  float* out = (float*)d_out;
  char* ws = (char*)d_ws;

  u16*   aB   = (u16*)ws;                       // 33,554,432 B  inputs bf16 [M][K]
  u16*   wBt  = (u16*)(ws + 33554432);          //  4,194,304 B  weights bf16 [N][K]
  u16*   vb   = (u16*)(ws + 37748736);          // 33,554,432 B  v bf16 [b,h,t,d]
  float* pb   = (float*)(ws + 71303168);        //  1,048,576 B  p=exp(s) [b,h,t]
  float* aggU = (float*)(ws + 72351744);        //     16,384 B
  float* aggW = (float*)(ws + 72368128);        //  1,048,576 B  (ends ~73.4 MB)

  prep<<<10240, 256, 0, stream>>>(inputs, kvk, aB, wBt);
  gemm_kv<<<512, 1024, 98304, stream>>>(aB, wBt, qk, pb, vb, aggU, aggW);
  scan_pass3<<<B_*C_, 1024, 0, stream>>>(vb, pb, aggU, aggW, out);
}